// Round 2
// baseline (581.993 us; speedup 1.0000x reference)
//
#include <hip/hip_runtime.h>
#include <math.h>

#define B_  8
#define T_  2048
#define S_  2048
#define D_  512

typedef _Float16 half8   __attribute__((ext_vector_type(8)));
typedef _Float16 half4_t __attribute__((ext_vector_type(4)));
typedef float    floatx4 __attribute__((ext_vector_type(4)));

__device__ __forceinline__ floatx4 mfma16(half8 a, half8 b, floatx4 c) {
  return __builtin_amdgcn_mfma_f32_16x16x32_f16(a, b, c, 0, 0, 0);
}

// ---------------------------------------------------------------------------
// Kernel 1: Vt[b][d][s] = (fp16) attn[b][s][d]
// ---------------------------------------------------------------------------
__global__ __launch_bounds__(256) void transpose_cast_kernel(
    const float* __restrict__ attn, _Float16* __restrict__ Vt) {
  __shared__ _Float16 tile[32][33];
  const int tx = threadIdx.x, ty = threadIdx.y;
  const int b = blockIdx.z, s0 = blockIdx.y * 32, d0 = blockIdx.x * 32;
  const float* src = attn + ((size_t)b * S_ + s0) * D_ + d0;
#pragma unroll
  for (int i = 0; i < 4; ++i) {
    int s = ty + i * 8;
    tile[tx][s] = (_Float16)src[(size_t)s * D_ + tx];
  }
  __syncthreads();
  _Float16* dst = Vt + ((size_t)b * D_ + d0) * S_ + s0;
#pragma unroll
  for (int i = 0; i < 4; ++i) {
    int d = ty + i * 8;
    dst[(size_t)d * S_ + tx] = tile[d][tx];
  }
}

// ---------------------------------------------------------------------------
// Kernel 2: K16[i][e] = (fp16)( sum_d attn[i][d] * W[e][d] + bias[e] )
//   block tile 128x128, 8 waves (512 thr) each 64x32 -> 16 waves/CU.
// ---------------------------------------------------------------------------
__global__ __launch_bounds__(512, 2) void keys_gemm_kernel(
    const float* __restrict__ X, const float* __restrict__ W,
    const float* __restrict__ bias, _Float16* __restrict__ K16) {
  __shared__ alignas(16) _Float16 Xs[128][72];
  __shared__ alignas(16) _Float16 Ws[128][72];
  const int t = threadIdx.x;
  const int wave = t >> 6, lane = t & 63, q = lane >> 4, n = lane & 15;
  const int wm = wave >> 2, wn = wave & 3;   // 2 x 4 wave grid, wave tile 64x32
  const int m0 = blockIdx.x * 128, n0 = blockIdx.y * 128;

  floatx4 acc[4][2];
#pragma unroll
  for (int i = 0; i < 4; ++i)
#pragma unroll
    for (int j = 0; j < 2; ++j) {
      floatx4 z = {0.f, 0.f, 0.f, 0.f};
      acc[i][j] = z;
    }

  for (int kc = 0; kc < 8; ++kc) {
    const int k0 = kc * 64;
#pragma unroll
    for (int i = 0; i < 4; ++i) {
      int seg = i * 512 + t;           // 2048 segs: 128 rows x 16 float4
      int row = seg >> 4, c4 = (seg & 15) * 4;
      floatx4 xv = *(const floatx4*)&X[(size_t)(m0 + row) * D_ + k0 + c4];
      floatx4 wv = *(const floatx4*)&W[(size_t)(n0 + row) * D_ + k0 + c4];
      half4_t xh, wh;
#pragma unroll
      for (int j = 0; j < 4; ++j) { xh[j] = (_Float16)xv[j]; wh[j] = (_Float16)wv[j]; }
      *(half4_t*)&Xs[row][c4] = xh;
      *(half4_t*)&Ws[row][c4] = wh;
    }
    __syncthreads();
#pragma unroll
    for (int kk = 0; kk < 2; ++kk) {
      half8 a[4], bb[2];
#pragma unroll
      for (int mt = 0; mt < 4; ++mt)
        a[mt] = *(const half8*)&Xs[wm * 64 + mt * 16 + n][kk * 32 + q * 8];
#pragma unroll
      for (int nt = 0; nt < 2; ++nt)
        bb[nt] = *(const half8*)&Ws[wn * 32 + nt * 16 + n][kk * 32 + q * 8];
#pragma unroll
      for (int mt = 0; mt < 4; ++mt)
#pragma unroll
        for (int nt = 0; nt < 2; ++nt)
          acc[mt][nt] = mfma16(a[mt], bb[nt], acc[mt][nt]);
    }
    __syncthreads();
  }

#pragma unroll
  for (int nt = 0; nt < 2; ++nt) {
    int col = n0 + wn * 32 + nt * 16 + n;
    float bv = bias[col];
#pragma unroll
    for (int mt = 0; mt < 4; ++mt)
#pragma unroll
      for (int r = 0; r < 4; ++r) {
        int row = m0 + wm * 64 + mt * 16 + q * 4 + r;
        K16[(size_t)row * D_ + col] = (_Float16)(acc[mt][nt][r] + bv);
      }
  }
}

// ---------------------------------------------------------------------------
// Kernel 3: flash attention.
//   BM=16 rows/block (grid 1024 -> 16 waves/CU), s-tiles of 256 (each wave
//   owns 64 score cols), Q resident in LDS (fp16), K/V fragments from global,
//   double-buffered Ps/redmax -> only 2 barriers per s-tile, wave-private l.
// ---------------------------------------------------------------------------
__global__ __launch_bounds__(256, 4) void flash_kernel(
    const float* __restrict__ Qf, const _Float16* __restrict__ K16,
    const _Float16* __restrict__ Vt, float* __restrict__ out) {
  __shared__ alignas(16) _Float16 Qs[16][520];
  __shared__ alignas(16) _Float16 Ps[2][16][264];
  __shared__ alignas(16) float redmax[2][16][4];
  __shared__ alignas(16) float lsum[16][4];

  const int t = threadIdx.x;
  const int wave = t >> 6, lane = t & 63, q = lane >> 4, n = lane & 15;
  const int bid = blockIdx.x;
  const int b = bid & 7;            // batch = bid%8 -> one batch per XCD (L2 locality)
  const int t0 = (bid >> 3) * 16;

  // ---- stage Q (fp32 -> fp16) into LDS, resident for whole kernel ----
  const float* Qbase = Qf + ((size_t)b * T_ + t0) * D_;
#pragma unroll
  for (int i = 0; i < 8; ++i) {
    int seg = i * 256 + t;               // 2048 segs: 16 rows x 128 float4
    int row = seg >> 7, c4 = (seg & 127) * 4;
    floatx4 v = *(const floatx4*)&Qbase[(size_t)row * D_ + c4];
    half4_t h;
#pragma unroll
    for (int j = 0; j < 4; ++j) h[j] = (_Float16)v[j];
    *(half4_t*)&Qs[row][c4] = h;
  }

  floatx4 O[8];
#pragma unroll
  for (int ng = 0; ng < 8; ++ng) {
    floatx4 z = {0.f, 0.f, 0.f, 0.f};
    O[ng] = z;
  }
  float mst[4], lst[4], alpha[4];
#pragma unroll
  for (int r = 0; r < 4; ++r) { mst[r] = -INFINITY; lst[r] = 0.f; }

  __syncthreads();

  const _Float16* Kb = K16 + (size_t)b * S_ * D_;
  const _Float16* Vb = Vt + (size_t)b * D_ * S_;

  for (int st = 0; st < S_ / 256; ++st) {
    const int s0 = st * 256;
    const int slot = st & 1;

    // ------- QK^T: wave computes 16 rows x 64 cols [s0+64w, s0+64w+64) ----
    floatx4 Sc[4];
#pragma unroll
    for (int nt = 0; nt < 4; ++nt) {
      floatx4 z = {0.f, 0.f, 0.f, 0.f};
      Sc[nt] = z;
    }
    const _Float16* kp = Kb + (size_t)(s0 + wave * 64 + n) * D_ + q * 8;
#pragma unroll 2
    for (int kk = 0; kk < 16; ++kk) {
      half8 a = *(const half8*)&Qs[n][kk * 32 + q * 8];
#pragma unroll
      for (int nt = 0; nt < 4; ++nt) {
        half8 bf = *(const half8*)(kp + (size_t)(nt * 16) * D_ + kk * 32);
        Sc[nt] = mfma16(a, bf, Sc[nt]);
      }
    }

    // ------- local row max over this wave's 64 cols -----------------------
#pragma unroll
    for (int r = 0; r < 4; ++r) {
      float v = fmaxf(fmaxf(Sc[0][r], Sc[1][r]), fmaxf(Sc[2][r], Sc[3][r]));
      v = fmaxf(v, __shfl_xor(v, 1, 16));
      v = fmaxf(v, __shfl_xor(v, 2, 16));
      v = fmaxf(v, __shfl_xor(v, 4, 16));
      v = fmaxf(v, __shfl_xor(v, 8, 16));
      if (n == 0) redmax[slot][q * 4 + r][wave] = v;
    }
    __syncthreads();   // barrier A (also WAR-protects Ps[slot] from tile st-2)

    // ------- shared m update, P = exp, wave-private l ---------------------
#pragma unroll
    for (int r = 0; r < 4; ++r) {
      int row = q * 4 + r;
      floatx4 rm = *(const floatx4*)&redmax[slot][row][0];
      float tm = fmaxf(fmaxf(rm[0], rm[1]), fmaxf(rm[2], rm[3]));
      float mn = fmaxf(mst[r], tm);
      alpha[r] = __expf(mst[r] - mn);
      mst[r] = mn;
    }
#pragma unroll
    for (int r = 0; r < 4; ++r) {
      int row = q * 4 + r;
      float s = 0.f;
#pragma unroll
      for (int nt = 0; nt < 4; ++nt) {
        float p = __expf(Sc[nt][r] - mst[r]);
        Ps[slot][row][wave * 64 + nt * 16 + n] = (_Float16)p;
        s += p;
      }
      s += __shfl_xor(s, 1, 16);
      s += __shfl_xor(s, 2, 16);
      s += __shfl_xor(s, 4, 16);
      s += __shfl_xor(s, 8, 16);
      lst[r] = lst[r] * alpha[r] + s;   // wave-private partial denominator
    }

    // rescale O by alpha
#pragma unroll
    for (int ng = 0; ng < 8; ++ng)
#pragma unroll
      for (int r = 0; r < 4; ++r) O[ng][r] *= alpha[r];

    __syncthreads();   // barrier B: all Ps[slot] written

    // ------- PV: O[16 x 128 d-cols per wave] += P(16x256) @ V(256x128) ----
    const _Float16* vp = Vb + (size_t)(wave * 128 + n) * S_ + s0 + q * 8;
#pragma unroll 2
    for (int kk = 0; kk < 8; ++kk) {
      half8 a = *(const half8*)&Ps[slot][n][kk * 32 + q * 8];
#pragma unroll
      for (int ng = 0; ng < 8; ++ng) {
        half8 bv = *(const half8*)(vp + (size_t)(ng * 16) * S_ + kk * 32);
        O[ng] = mfma16(a, bv, O[ng]);
      }
    }
    // no barrier here: next tile's barrier A provides WAR protection
  }

  // ---- combine wave-private l, then out = O / l ----
#pragma unroll
  for (int r = 0; r < 4; ++r)
    if (n == 0) lsum[q * 4 + r][wave] = lst[r];
  __syncthreads();

  float* ob = out + ((size_t)b * T_ + t0) * D_;
#pragma unroll
  for (int r = 0; r < 4; ++r) {
    int row = q * 4 + r;
    floatx4 ls = *(const floatx4*)&lsum[row][0];
    float inv = 1.f / (ls[0] + ls[1] + ls[2] + ls[3]);
#pragma unroll
    for (int ng = 0; ng < 8; ++ng)
      ob[(size_t)row * D_ + wave * 128 + ng * 16 + n] = O[ng][r] * inv;
  }
}

// ---------------------------------------------------------------------------
extern "C" void kernel_launch(void* const* d_in, const int* in_sizes, int n_in,
                              void* d_out, int out_size, void* d_ws, size_t ws_size,
                              hipStream_t stream) {
  (void)in_sizes; (void)n_in; (void)out_size; (void)ws_size;
  const float* main_in = (const float*)d_in[0];   // [B,T,D]
  const float* attn_in = (const float*)d_in[1];   // [B,S,D]
  const float* W_f     = (const float*)d_in[2];   // [D,D]
  const float* b_f     = (const float*)d_in[3];   // [D]
  float* out = (float*)d_out;                     // [B,T,D] fp32

  _Float16* K16 = (_Float16*)d_ws;                       // [B*S, D] fp16
  _Float16* Vt  = K16 + (size_t)B_ * S_ * D_;            // [B, D, S] fp16

  transpose_cast_kernel<<<dim3(D_ / 32, S_ / 32, B_), dim3(32, 8, 1), 0, stream>>>(
      attn_in, Vt);
  keys_gemm_kernel<<<dim3((B_ * S_) / 128, D_ / 128), 512, 0, stream>>>(
      attn_in, W_f, b_f, K16);
  flash_kernel<<<(B_ * T_) / 16, 256, 0, stream>>>(main_in, K16, Vt, out);
}

// Round 3
// 356.823 us; speedup vs baseline: 1.6310x; 1.6310x over previous
//
#include <hip/hip_runtime.h>
#include <math.h>

#define B_  8
#define T_  2048
#define S_  2048
#define D_  512

typedef _Float16 half8   __attribute__((ext_vector_type(8)));
typedef _Float16 half4_t __attribute__((ext_vector_type(4)));
typedef float    floatx4 __attribute__((ext_vector_type(4)));

__device__ __forceinline__ floatx4 mfma16(half8 a, half8 b, floatx4 c) {
  return __builtin_amdgcn_mfma_f32_16x16x32_f16(a, b, c, 0, 0, 0);
}

// async global->LDS, 16B per lane; lds base must be wave-uniform (HW adds lane*16)
__device__ __forceinline__ void async16(void* lds, const void* g) {
  __builtin_amdgcn_global_load_lds(
      (const __attribute__((address_space(1))) void*)g,
      (__attribute__((address_space(3))) void*)lds, 16, 0, 0);
}

// ---------------------------------------------------------------------------
// Kernel 1: Vt[b][d][s] = (fp16) attn[b][s][d]
// ---------------------------------------------------------------------------
__global__ __launch_bounds__(256) void transpose_cast_kernel(
    const float* __restrict__ attn, _Float16* __restrict__ Vt) {
  __shared__ _Float16 tile[32][33];
  const int tx = threadIdx.x, ty = threadIdx.y;
  const int b = blockIdx.z, s0 = blockIdx.y * 32, d0 = blockIdx.x * 32;
  const float* src = attn + ((size_t)b * S_ + s0) * D_ + d0;
#pragma unroll
  for (int i = 0; i < 4; ++i) {
    int s = ty + i * 8;
    tile[tx][s] = (_Float16)src[(size_t)s * D_ + tx];
  }
  __syncthreads();
  _Float16* dst = Vt + ((size_t)b * D_ + d0) * S_ + s0;
#pragma unroll
  for (int i = 0; i < 4; ++i) {
    int d = ty + i * 8;
    dst[(size_t)d * S_ + tx] = tile[d][tx];
  }
}

// ---------------------------------------------------------------------------
// Kernel 2: K16[i][e] = (fp16)( sum_d attn[i][d] * W[e][d] + bias[e] )
// ---------------------------------------------------------------------------
__global__ __launch_bounds__(512, 2) void keys_gemm_kernel(
    const float* __restrict__ X, const float* __restrict__ W,
    const float* __restrict__ bias, _Float16* __restrict__ K16) {
  __shared__ alignas(16) _Float16 Xs[128][72];
  __shared__ alignas(16) _Float16 Ws[128][72];
  const int t = threadIdx.x;
  const int wave = t >> 6, lane = t & 63, q = lane >> 4, n = lane & 15;
  const int wm = wave >> 2, wn = wave & 3;
  const int m0 = blockIdx.x * 128, n0 = blockIdx.y * 128;

  floatx4 acc[4][2];
#pragma unroll
  for (int i = 0; i < 4; ++i)
#pragma unroll
    for (int j = 0; j < 2; ++j) {
      floatx4 z = {0.f, 0.f, 0.f, 0.f};
      acc[i][j] = z;
    }

  for (int kc = 0; kc < 8; ++kc) {
    const int k0 = kc * 64;
#pragma unroll
    for (int i = 0; i < 4; ++i) {
      int seg = i * 512 + t;
      int row = seg >> 4, c4 = (seg & 15) * 4;
      floatx4 xv = *(const floatx4*)&X[(size_t)(m0 + row) * D_ + k0 + c4];
      floatx4 wv = *(const floatx4*)&W[(size_t)(n0 + row) * D_ + k0 + c4];
      half4_t xh, wh;
#pragma unroll
      for (int j = 0; j < 4; ++j) { xh[j] = (_Float16)xv[j]; wh[j] = (_Float16)wv[j]; }
      *(half4_t*)&Xs[row][c4] = xh;
      *(half4_t*)&Ws[row][c4] = wh;
    }
    __syncthreads();
#pragma unroll
    for (int kk = 0; kk < 2; ++kk) {
      half8 a[4], bb[2];
#pragma unroll
      for (int mt = 0; mt < 4; ++mt)
        a[mt] = *(const half8*)&Xs[wm * 64 + mt * 16 + n][kk * 32 + q * 8];
#pragma unroll
      for (int nt = 0; nt < 2; ++nt)
        bb[nt] = *(const half8*)&Ws[wn * 32 + nt * 16 + n][kk * 32 + q * 8];
#pragma unroll
      for (int mt = 0; mt < 4; ++mt)
#pragma unroll
        for (int nt = 0; nt < 2; ++nt)
          acc[mt][nt] = mfma16(a[mt], bb[nt], acc[mt][nt]);
    }
    __syncthreads();
  }

#pragma unroll
  for (int nt = 0; nt < 2; ++nt) {
    int col = n0 + wn * 32 + nt * 16 + n;
    float bv = bias[col];
#pragma unroll
    for (int mt = 0; mt < 4; ++mt)
#pragma unroll
      for (int r = 0; r < 4; ++r) {
        int row = m0 + wm * 64 + mt * 16 + q * 4 + r;
        K16[(size_t)row * D_ + col] = (_Float16)(acc[mt][nt][r] + bv);
      }
  }
}

// ---------------------------------------------------------------------------
// Kernel 3: flash attention, LDS-staged K/V (global_load_lds, double-buffered)
//   grid 256 = 1 block/CU, 512 thr / 8 waves, BM=64 Q rows, BN=32 s per tile.
//   Q in registers (wave role: strip=w&3 rows, half=w>>2 cols for QK).
//   O in registers (wave owns d-cols [w*64, w*64+64) for PV).
//   2 barriers per s-tile: MID (redmax + K/V drain), C (Ps visible).
// ---------------------------------------------------------------------------
__global__ __launch_bounds__(512, 2) void flash_kernel(
    const float* __restrict__ Qf, const _Float16* __restrict__ K16,
    const _Float16* __restrict__ Vt, float* __restrict__ out) {
  __shared__ _Float16 Klds[2][32][544];   // 32 s-rows x 512 d, pad 32 halfs/row
  __shared__ _Float16 Vlds[2][512][32];   // 512 d-rows x 32 s
  __shared__ _Float16 Ps[2][64][32];
  __shared__ float redmax[2][64][2];
  __shared__ float lsum[64][2];

  const int t = threadIdx.x;
  const int w = t >> 6, lane = t & 63, q = lane >> 4, n = lane & 15;
  const int strip = w & 3, half = w >> 2;
  const int bid = blockIdx.x;
  const int b = bid & 7, t0 = (bid >> 3) * 64;

  const _Float16* Kb = K16 + (size_t)b * S_ * D_;
  const _Float16* Vb = Vt + (size_t)b * D_ * S_;

  // ---- Q -> registers (16 k-chunks of 32, fp32 -> fp16) ----
  half8 qreg[16];
  {
    const float* qrow = Qf + ((size_t)b * T_ + t0 + strip * 16 + n) * D_;
#pragma unroll
    for (int kk = 0; kk < 16; ++kk) {
      floatx4 v0 = *(const floatx4*)&qrow[kk * 32 + q * 8];
      floatx4 v1 = *(const floatx4*)&qrow[kk * 32 + q * 8 + 4];
      half8 h;
#pragma unroll
      for (int j = 0; j < 4; ++j) { h[j] = (_Float16)v0[j]; h[j + 4] = (_Float16)v1[j]; }
      qreg[kk] = h;
    }
  }

  floatx4 O[4][4];
#pragma unroll
  for (int mt = 0; mt < 4; ++mt)
#pragma unroll
    for (int ng = 0; ng < 4; ++ng) {
      floatx4 z = {0.f, 0.f, 0.f, 0.f};
      O[mt][ng] = z;
    }
  float m_st[4][4], lst[4];
#pragma unroll
  for (int mt = 0; mt < 4; ++mt)
#pragma unroll
    for (int r = 0; r < 4; ++r) m_st[mt][r] = -1e30f;
#pragma unroll
  for (int r = 0; r < 4; ++r) lst[r] = 0.f;

  // ---- prologue staging: K[0], V[0] ----
#pragma unroll
  for (int i = 0; i < 4; ++i) {
    int row = w * 4 + i;
    async16(&Klds[0][row][0], Kb + (size_t)row * D_ + lane * 8);
  }
#pragma unroll
  for (int i = 0; i < 4; ++i) {
    int D0 = (w * 4 + i) * 16;
    async16(&Vlds[0][D0][0], Vb + (size_t)(D0 + (lane >> 2)) * S_ + (lane & 3) * 8);
  }
  __syncthreads();

  for (int st = 0; st < S_ / 32; ++st) {
    const int cur = st & 1, nxt = cur ^ 1;
    const int s0 = st * 32;

    // prefetch next K tile (in flight during QK; drained at MID)
    if (st < S_ / 32 - 1) {
#pragma unroll
      for (int i = 0; i < 4; ++i) {
        int row = w * 4 + i;
        async16(&Klds[nxt][row][0], Kb + (size_t)(s0 + 32 + row) * D_ + lane * 8);
      }
    }

    // ---- QK^T: wave = 16 rows (strip) x 16 cols (half) ----
    floatx4 Sc = {0.f, 0.f, 0.f, 0.f};
#pragma unroll
    for (int kk = 0; kk < 16; ++kk) {
      half8 bf = *(const half8*)&Klds[cur][half * 16 + n][kk * 32 + q * 8];
      Sc = mfma16(qreg[kk], bf, Sc);
    }

    // partial row max over this wave's 16 cols
#pragma unroll
    for (int r = 0; r < 4; ++r) {
      float v = Sc[r];
      v = fmaxf(v, __shfl_xor(v, 1, 16));
      v = fmaxf(v, __shfl_xor(v, 2, 16));
      v = fmaxf(v, __shfl_xor(v, 4, 16));
      v = fmaxf(v, __shfl_xor(v, 8, 16));
      if (n == 0) redmax[cur][strip * 16 + q * 4 + r][half] = v;
    }

    __syncthreads();   // MID: redmax visible; drains K[nxt] + V[cur] loads

    // ---- m/alpha update for ALL 64 rows (wave-local, from redmax) ----
    float alpha[4][4];
#pragma unroll
    for (int mt = 0; mt < 4; ++mt) {
      floatx4 a0 = *(const floatx4*)&redmax[cur][mt * 16 + q * 4][0];
      floatx4 a1 = *(const floatx4*)&redmax[cur][mt * 16 + q * 4 + 2][0];
      float nm0 = fmaxf(a0[0], a0[1]), nm1 = fmaxf(a0[2], a0[3]);
      float nm2 = fmaxf(a1[0], a1[1]), nm3 = fmaxf(a1[2], a1[3]);
      float nm[4] = {nm0, nm1, nm2, nm3};
#pragma unroll
      for (int r = 0; r < 4; ++r) {
        float mn = fmaxf(m_st[mt][r], nm[r]);
        alpha[mt][r] = __expf(m_st[mt][r] - mn);
        m_st[mt][r] = mn;
      }
    }

    // ---- P = exp(S - m) for own strip; wave-private l update ----
#pragma unroll
    for (int r = 0; r < 4; ++r) {
      float p = __expf(Sc[r] - m_st[strip][r]);
      Ps[cur][strip * 16 + q * 4 + r][half * 16 + n] = (_Float16)p;
      float s = p;
      s += __shfl_xor(s, 1, 16);
      s += __shfl_xor(s, 2, 16);
      s += __shfl_xor(s, 4, 16);
      s += __shfl_xor(s, 8, 16);
      lst[r] = lst[r] * alpha[strip][r] + s;
    }

    // ---- rescale O ----
#pragma unroll
    for (int mt = 0; mt < 4; ++mt)
#pragma unroll
      for (int ng = 0; ng < 4; ++ng)
#pragma unroll
        for (int r = 0; r < 4; ++r) O[mt][ng][r] *= alpha[mt][r];

    __syncthreads();   // C: Ps visible (vmcnt already 0 -> cheap)

    // prefetch next V tile (in flight during PV + next QK; drained next MID)
    if (st < S_ / 32 - 1) {
#pragma unroll
      for (int i = 0; i < 4; ++i) {
        int D0 = (w * 4 + i) * 16;
        async16(&Vlds[nxt][D0][0],
                Vb + (size_t)(D0 + (lane >> 2)) * S_ + s0 + 32 + (lane & 3) * 8);
      }
    }

    // ---- PV: O(64 rows x 64 d-cols per wave) += P(64x32) @ V(32x64) ----
    half8 av[4];
#pragma unroll
    for (int mt = 0; mt < 4; ++mt)
      av[mt] = *(const half8*)&Ps[cur][mt * 16 + n][q * 8];
#pragma unroll
    for (int ng = 0; ng < 4; ++ng) {
      half8 bv = *(const half8*)&Vlds[cur][w * 64 + ng * 16 + n][q * 8];
#pragma unroll
      for (int mt = 0; mt < 4; ++mt)
        O[mt][ng] = mfma16(av[mt], bv, O[mt][ng]);
    }
  }

  // ---- epilogue: combine wave-private l halves, write out ----
  if (n == 0) {
#pragma unroll
    for (int r = 0; r < 4; ++r) lsum[strip * 16 + q * 4 + r][half] = lst[r];
  }
  __syncthreads();

  float* ob = out + ((size_t)b * T_ + t0) * D_;
#pragma unroll
  for (int mt = 0; mt < 4; ++mt) {
    floatx4 a0 = *(const floatx4*)&lsum[mt * 16 + q * 4][0];
    floatx4 a1 = *(const floatx4*)&lsum[mt * 16 + q * 4 + 2][0];
    float linv[4] = {1.f / (a0[0] + a0[1]), 1.f / (a0[2] + a0[3]),
                     1.f / (a1[0] + a1[1]), 1.f / (a1[2] + a1[3])};
#pragma unroll
    for (int ng = 0; ng < 4; ++ng)
#pragma unroll
      for (int r = 0; r < 4; ++r)
        ob[(size_t)(mt * 16 + q * 4 + r) * D_ + w * 64 + ng * 16 + n] =
            O[mt][ng][r] * linv[r];
  }
}

// ---------------------------------------------------------------------------
extern "C" void kernel_launch(void* const* d_in, const int* in_sizes, int n_in,
                              void* d_out, int out_size, void* d_ws, size_t ws_size,
                              hipStream_t stream) {
  (void)in_sizes; (void)n_in; (void)out_size; (void)ws_size;
  const float* main_in = (const float*)d_in[0];   // [B,T,D]
  const float* attn_in = (const float*)d_in[1];   // [B,S,D]
  const float* W_f     = (const float*)d_in[2];   // [D,D]
  const float* b_f     = (const float*)d_in[3];   // [D]
  float* out = (float*)d_out;                     // [B,T,D] fp32

  _Float16* K16 = (_Float16*)d_ws;                       // [B*S, D] fp16
  _Float16* Vt  = K16 + (size_t)B_ * S_ * D_;            // [B, D, S] fp16

  transpose_cast_kernel<<<dim3(D_ / 32, S_ / 32, B_), dim3(32, 8, 1), 0, stream>>>(
      attn_in, Vt);
  keys_gemm_kernel<<<dim3((B_ * S_) / 128, D_ / 128), 512, 0, stream>>>(
      attn_in, W_f, b_f, K16);
  flash_kernel<<<(B_ * T_) / 64, 512, 0, stream>>>(main_in, K16, Vt, out);
}

// Round 4
// 314.190 us; speedup vs baseline: 1.8524x; 1.1357x over previous
//
#include <hip/hip_runtime.h>
#include <math.h>

#define B_  8
#define T_  2048
#define S_  2048
#define D_  512

typedef _Float16 half8   __attribute__((ext_vector_type(8)));
typedef _Float16 half4_t __attribute__((ext_vector_type(4)));
typedef float    floatx4 __attribute__((ext_vector_type(4)));

__device__ __forceinline__ floatx4 mfma16(half8 a, half8 b, floatx4 c) {
  return __builtin_amdgcn_mfma_f32_16x16x32_f16(a, b, c, 0, 0, 0);
}

// async global->LDS, 16B per lane; lds base must be wave-uniform (HW adds lane*16)
__device__ __forceinline__ void async16(void* lds, const void* g) {
  __builtin_amdgcn_global_load_lds(
      (const __attribute__((address_space(1))) void*)g,
      (__attribute__((address_space(3))) void*)lds, 16, 0, 0);
}

// ---------------------------------------------------------------------------
// Kernel 1: Vt[b][d][s] = (fp16) attn[b][s][d]
// ---------------------------------------------------------------------------
__global__ __launch_bounds__(256) void transpose_cast_kernel(
    const float* __restrict__ attn, _Float16* __restrict__ Vt) {
  __shared__ _Float16 tile[32][33];
  const int tx = threadIdx.x, ty = threadIdx.y;
  const int b = blockIdx.z, s0 = blockIdx.y * 32, d0 = blockIdx.x * 32;
  const float* src = attn + ((size_t)b * S_ + s0) * D_ + d0;
#pragma unroll
  for (int i = 0; i < 4; ++i) {
    int s = ty + i * 8;
    tile[tx][s] = (_Float16)src[(size_t)s * D_ + tx];
  }
  __syncthreads();
  _Float16* dst = Vt + ((size_t)b * D_ + d0) * S_ + s0;
#pragma unroll
  for (int i = 0; i < 4; ++i) {
    int d = ty + i * 8;
    dst[(size_t)d * S_ + tx] = tile[d][tx];
  }
}

// ---------------------------------------------------------------------------
// Kernel 2: K16[i][e] = (fp16)( sum_d attn[i][d] * W[e][d] + bias[e] )
// ---------------------------------------------------------------------------
__global__ __launch_bounds__(512, 2) void keys_gemm_kernel(
    const float* __restrict__ X, const float* __restrict__ W,
    const float* __restrict__ bias, _Float16* __restrict__ K16) {
  __shared__ alignas(16) _Float16 Xs[128][72];
  __shared__ alignas(16) _Float16 Ws[128][72];
  const int t = threadIdx.x;
  const int wave = t >> 6, lane = t & 63, q = lane >> 4, n = lane & 15;
  const int wm = wave >> 2, wn = wave & 3;
  const int m0 = blockIdx.x * 128, n0 = blockIdx.y * 128;

  floatx4 acc[4][2];
#pragma unroll
  for (int i = 0; i < 4; ++i)
#pragma unroll
    for (int j = 0; j < 2; ++j) {
      floatx4 z = {0.f, 0.f, 0.f, 0.f};
      acc[i][j] = z;
    }

  for (int kc = 0; kc < 8; ++kc) {
    const int k0 = kc * 64;
#pragma unroll
    for (int i = 0; i < 4; ++i) {
      int seg = i * 512 + t;
      int row = seg >> 4, c4 = (seg & 15) * 4;
      floatx4 xv = *(const floatx4*)&X[(size_t)(m0 + row) * D_ + k0 + c4];
      floatx4 wv = *(const floatx4*)&W[(size_t)(n0 + row) * D_ + k0 + c4];
      half4_t xh, wh;
#pragma unroll
      for (int j = 0; j < 4; ++j) { xh[j] = (_Float16)xv[j]; wh[j] = (_Float16)wv[j]; }
      *(half4_t*)&Xs[row][c4] = xh;
      *(half4_t*)&Ws[row][c4] = wh;
    }
    __syncthreads();
#pragma unroll
    for (int kk = 0; kk < 2; ++kk) {
      half8 a[4], bb[2];
#pragma unroll
      for (int mt = 0; mt < 4; ++mt)
        a[mt] = *(const half8*)&Xs[wm * 64 + mt * 16 + n][kk * 32 + q * 8];
#pragma unroll
      for (int nt = 0; nt < 2; ++nt)
        bb[nt] = *(const half8*)&Ws[wn * 32 + nt * 16 + n][kk * 32 + q * 8];
#pragma unroll
      for (int mt = 0; mt < 4; ++mt)
#pragma unroll
        for (int nt = 0; nt < 2; ++nt)
          acc[mt][nt] = mfma16(a[mt], bb[nt], acc[mt][nt]);
    }
    __syncthreads();
  }

#pragma unroll
  for (int nt = 0; nt < 2; ++nt) {
    int col = n0 + wn * 32 + nt * 16 + n;
    float bv = bias[col];
#pragma unroll
    for (int mt = 0; mt < 4; ++mt)
#pragma unroll
      for (int r = 0; r < 4; ++r) {
        int row = m0 + wm * 64 + mt * 16 + q * 4 + r;
        K16[(size_t)row * D_ + col] = (_Float16)(acc[mt][nt][r] + bv);
      }
  }
}

// ---------------------------------------------------------------------------
// Kernel 3: flash attention — wave-independent rows, 1 barrier/tile.
//   Block = 256 thr / 4 waves, BM=64 (wave owns 16 rows end-to-end), BN=32.
//   K/V double-buffered in LDS via async16 with XOR-swizzled chunk layout
//   (conflict-free reads, no padding). Q + O(16x512) + l in registers.
//   l computed via MFMA against constant ones fragment. No cross-wave softmax.
// ---------------------------------------------------------------------------
__global__ __launch_bounds__(256, 1) void flash_kernel(
    const float* __restrict__ Qf, const _Float16* __restrict__ K16,
    const _Float16* __restrict__ Vt, float* __restrict__ out) {
  // Klds row = 32 chunks of 16B, chunk slot l holds source chunk (l ^ (srow&7))
  __shared__ _Float16 Klds[2][32][512];
  // Vlds row (d) = 4 chunks of 16B, slot c holds source s-chunk (c ^ ((d>>1)&3))
  __shared__ _Float16 Vlds[2][512][32];
  __shared__ _Float16 Pscr[4][16][40];   // per-wave P transpose scratch

  const int t = threadIdx.x;
  const int w = t >> 6, lane = t & 63, qd = lane >> 4, n = lane & 15;
  const int n7 = n & 7;
  const int bid = blockIdx.x;
  const int b = bid & 7, t0 = (bid >> 3) * 64;

  const _Float16* Kb = K16 + (size_t)b * S_ * D_;
  const _Float16* Vb = Vt + (size_t)b * D_ * S_;

  // per-lane swizzle constants
  const int ksw = lane ^ 0;                      // staging: chunk = lane ^ (row&7)
  const int vsw = (lane & 3) ^ ((lane >> 3) & 3);  // staging V source s-chunk
  const int ccV = qd ^ ((n >> 1) & 3);           // V read slot

  // ---- Q -> registers (wave's 16 rows; A-frag row = lane&15) ----
  half8 qreg[16];
  {
    const float* qrow = Qf + ((size_t)b * T_ + t0 + w * 16 + n) * D_;
#pragma unroll
    for (int kk = 0; kk < 16; ++kk) {
      floatx4 v0 = *(const floatx4*)&qrow[kk * 32 + qd * 8];
      floatx4 v1 = *(const floatx4*)&qrow[kk * 32 + qd * 8 + 4];
      half8 h;
#pragma unroll
      for (int j = 0; j < 4; ++j) { h[j] = (_Float16)v0[j]; h[j + 4] = (_Float16)v1[j]; }
      qreg[kk] = h;
    }
  }

  floatx4 O[33];   // [0..31] = d-tiles, [32] = l (ones column)
#pragma unroll
  for (int ng = 0; ng < 33; ++ng) {
    floatx4 z = {0.f, 0.f, 0.f, 0.f};
    O[ng] = z;
  }
  float m_st[4];
#pragma unroll
  for (int r = 0; r < 4; ++r) m_st[r] = -1e30f;

  half8 ones8;
#pragma unroll
  for (int j = 0; j < 8; ++j) ones8[j] = (_Float16)1.0f;

  // ---- prologue staging: K[0], V[0] ----
#pragma unroll
  for (int i = 0; i < 8; ++i) {
    int row = w * 8 + i;
    async16(&Klds[0][row][0], Kb + (size_t)row * D_ + ((lane ^ (row & 7)) * 8));
  }
#pragma unroll
  for (int i = 0; i < 8; ++i) {
    int d0 = (w * 8 + i) * 16;
    async16(&Vlds[0][d0][0], Vb + (size_t)(d0 + (lane >> 2)) * S_ + vsw * 8);
  }
  __syncthreads();

  for (int st = 0; st < S_ / 32; ++st) {
    const int cur = st & 1, nxt = cur ^ 1;
    const int s0 = st * 32;

    // ---- prefetch next K+V tile (in flight during whole compute phase) ----
    if (st < S_ / 32 - 1) {
#pragma unroll
      for (int i = 0; i < 8; ++i) {
        int row = w * 8 + i;
        async16(&Klds[nxt][row][0],
                Kb + (size_t)(s0 + 32 + row) * D_ + ((lane ^ (row & 7)) * 8));
      }
#pragma unroll
      for (int i = 0; i < 8; ++i) {
        int d0 = (w * 8 + i) * 16;
        async16(&Vlds[nxt][d0][0],
                Vb + (size_t)(d0 + (lane >> 2)) * S_ + s0 + 32 + vsw * 8);
      }
    }

    // ---- QK^T: wave's 16 rows x 32 cols, 2 indep chains per col-tile ----
    floatx4 Sa0 = {0.f, 0.f, 0.f, 0.f}, Sa1 = Sa0, Sb0 = Sa0, Sb1 = Sa0;
#pragma unroll
    for (int kk = 0; kk < 8; ++kk) {
      int slot = (kk * 4 + qd) ^ n7;
      half8 b0 = *(const half8*)&Klds[cur][n][slot * 8];
      half8 b1 = *(const half8*)&Klds[cur][16 + n][slot * 8];
      Sa0 = mfma16(qreg[kk], b0, Sa0);
      Sa1 = mfma16(qreg[kk], b1, Sa1);
    }
#pragma unroll
    for (int kk = 8; kk < 16; ++kk) {
      int slot = (kk * 4 + qd) ^ n7;
      half8 b0 = *(const half8*)&Klds[cur][n][slot * 8];
      half8 b1 = *(const half8*)&Klds[cur][16 + n][slot * 8];
      Sb0 = mfma16(qreg[kk], b0, Sb0);
      Sb1 = mfma16(qreg[kk], b1, Sb1);
    }
    floatx4 Sc0 = Sa0 + Sb0, Sc1 = Sa1 + Sb1;

    // ---- wave-local online softmax (rows q*4+r, cols across 16 lanes) ----
    float alpha[4];
#pragma unroll
    for (int r = 0; r < 4; ++r) {
      float v = fmaxf(Sc0[r], Sc1[r]);
      v = fmaxf(v, __shfl_xor(v, 1, 16));
      v = fmaxf(v, __shfl_xor(v, 2, 16));
      v = fmaxf(v, __shfl_xor(v, 4, 16));
      v = fmaxf(v, __shfl_xor(v, 8, 16));
      float mn = fmaxf(m_st[r], v);
      alpha[r] = __expf(m_st[r] - mn);
      m_st[r] = mn;
    }

    // skip O-rescale when no row max changed (wave-uniform branch)
    bool unchanged = (alpha[0] == 1.f) & (alpha[1] == 1.f) &
                     (alpha[2] == 1.f) & (alpha[3] == 1.f);
    if (!__all(unchanged)) {
#pragma unroll
      for (int ng = 0; ng < 33; ++ng)
#pragma unroll
        for (int r = 0; r < 4; ++r) O[ng][r] *= alpha[r];
    }

    // ---- P = exp(S - m) -> wave-private scratch (C-layout -> A-layout) ----
#pragma unroll
    for (int r = 0; r < 4; ++r) {
      float p0 = __expf(Sc0[r] - m_st[r]);
      float p1 = __expf(Sc1[r] - m_st[r]);
      Pscr[w][qd * 4 + r][n] = (_Float16)p0;
      Pscr[w][qd * 4 + r][16 + n] = (_Float16)p1;
    }
    half8 av = *(const half8*)&Pscr[w][n][qd * 8];

    // ---- PV: O[16 rows x 512 d] += P(16x32) @ V(32x512), + l via ones ----
#pragma unroll
    for (int ng = 0; ng < 32; ++ng) {
      half8 bv = *(const half8*)&Vlds[cur][ng * 16 + n][ccV * 8];
      O[ng] = mfma16(av, bv, O[ng]);
    }
    O[32] = mfma16(av, ones8, O[32]);

    if (st < S_ / 32 - 1) __syncthreads();   // swap buffers (drains prefetch)
  }

  // ---- epilogue: out = O / l (l is lane-local in O[32], col-independent) ----
  float* ob = out + ((size_t)b * T_ + t0 + w * 16) * D_;
#pragma unroll
  for (int r = 0; r < 4; ++r) {
    float inv = 1.f / O[32][r];
    const size_t rowoff = (size_t)(qd * 4 + r) * D_;
#pragma unroll
    for (int ng = 0; ng < 32; ++ng)
      ob[rowoff + ng * 16 + n] = O[ng][r] * inv;
  }
}

// ---------------------------------------------------------------------------
extern "C" void kernel_launch(void* const* d_in, const int* in_sizes, int n_in,
                              void* d_out, int out_size, void* d_ws, size_t ws_size,
                              hipStream_t stream) {
  (void)in_sizes; (void)n_in; (void)out_size; (void)ws_size;
  const float* main_in = (const float*)d_in[0];   // [B,T,D]
  const float* attn_in = (const float*)d_in[1];   // [B,S,D]
  const float* W_f     = (const float*)d_in[2];   // [D,D]
  const float* b_f     = (const float*)d_in[3];   // [D]
  float* out = (float*)d_out;                     // [B,T,D] fp32

  _Float16* K16 = (_Float16*)d_ws;                       // [B*S, D] fp16
  _Float16* Vt  = K16 + (size_t)B_ * S_ * D_;            // [B, D, S] fp16

  transpose_cast_kernel<<<dim3(D_ / 32, S_ / 32, B_), dim3(32, 8, 1), 0, stream>>>(
      attn_in, Vt);
  keys_gemm_kernel<<<dim3((B_ * S_) / 128, D_ / 128), 512, 0, stream>>>(
      attn_in, W_f, b_f, K16);
  flash_kernel<<<(B_ * T_) / 64, 256, 0, stream>>>(main_in, K16, Vt, out);
}